// Round 4
// baseline (614.080 us; speedup 1.0000x reference)
//
#include <hip/hip_runtime.h>

// Problem constants
// x:(4096,8,1024) f32, U:(8,1048576,4) f32, V:(4,1048576,4) f32,
// scale:(8,1), biasq:(8,1), bias:(8,1024)  -> out:(4096,8,1024) f32
// D = 1024*1024 = 2^20, B=4096, N=8, K=4, BW=4, T=1.0

typedef __attribute__((ext_vector_type(8))) short short8;
typedef __attribute__((ext_vector_type(4))) float f32x4;
typedef __attribute__((ext_vector_type(4))) unsigned short ushort4v;

__device__ __forceinline__ unsigned short f2bf(float f) {
  union { float f; unsigned u; } a; a.f = f;
  unsigned u = a.u;
  u += 0x7fffu + ((u >> 16) & 1u);   // RNE; inputs are finite
  return (unsigned short)(u >> 16);
}

// ---------------------------------------------------------------------------
// Kernel 1: cast x fp32 -> bf16, repack [b][n][d1] -> [n][b][d1]
// ---------------------------------------------------------------------------
__global__ __launch_bounds__(256) void xcast_kernel(
    const float4* __restrict__ X4, ushort4v* __restrict__ Xb4) {
  const size_t idx = (size_t)blockIdx.x * 256 + threadIdx.x;  // 8388608 total
  const float4 v = X4[idx];
  const size_t flat = idx << 2;
  const int d1 = (int)(flat & 1023);
  const size_t nb = flat >> 10;
  const int nn = (int)(nb & 7);
  const size_t b = nb >> 3;
  ushort4v o;
  o.x = f2bf(v.x); o.y = f2bf(v.y); o.z = f2bf(v.z); o.w = f2bf(v.w);
  Xb4[(((size_t)nn << 22) + (b << 10) + (size_t)d1) >> 2] = o;
}

// ---------------------------------------------------------------------------
// Kernel 2: weight synthesis -> W^T bf16: Wt[n][l=d2][d1]
// ---------------------------------------------------------------------------
__global__ __launch_bounds__(256) void wgen_kernel(
    const float4* __restrict__ U4, const float4* __restrict__ V4,
    const float* __restrict__ scale, const float* __restrict__ biasq,
    unsigned short* __restrict__ Wt) {
  __shared__ float tiles[8][32][33];
  const int t = threadIdx.x;
  const int d1_0 = blockIdx.x * 32;
  const int d2_0 = blockIdx.y * 32;
#pragma unroll
  for (int i = 0; i < 4; i++) {
    const int e = t + 256 * i;
    const int r = e >> 5, c = e & 31;          // r: d1 offset, c: d2 offset
    const size_t d = (size_t)(d1_0 + r) * 1024 + (size_t)(d2_0 + c);
    float4 u[8];
#pragma unroll
    for (int nn = 0; nn < 8; nn++) u[nn] = U4[((size_t)nn << 20) + d];
    float integ[8];
#pragma unroll
    for (int nn = 0; nn < 8; nn++) integ[nn] = 0.f;
#pragma unroll
    for (int b = 0; b < 4; b++) {
      const float4 v = V4[((size_t)b << 20) + d];
      const float pw = (float)(1 << b);
#pragma unroll
      for (int nn = 0; nn < 8; nn++) {
        float th = u[nn].x * v.x + u[nn].y * v.y + u[nn].z * v.z + u[nn].w * v.w;
        th = fminf(10.f, fmaxf(-10.f, th));
        integ[nn] += pw / (1.f + __expf(-th));
      }
    }
#pragma unroll
    for (int nn = 0; nn < 8; nn++) tiles[nn][r][c] = integ[nn];
  }
  __syncthreads();
#pragma unroll
  for (int i = 0; i < 4; i++) {
    const int e = t + 256 * i;
    const int orow = e >> 5, oc = e & 31;      // orow: d2(l) offset, oc: d1 offset
#pragma unroll
    for (int nn = 0; nn < 8; nn++) {
      const float wval = scale[nn] * (tiles[nn][oc][orow] - biasq[nn] - 16.f);
      Wt[((size_t)nn << 20) + (size_t)(d2_0 + orow) * 1024 + (size_t)(d1_0 + oc)] =
          f2bf(wval);
    }
  }
}

// ---------------------------------------------------------------------------
// Kernel 3: batched bf16 GEMM -- DIRECT-FROM-GLOBAL fragments, NO LDS, NO
// BARRIERS. Each wave owns a 64x64 subtile: loads its A/B MFMA fragments
// straight from L1/L2 into registers (k-contiguous layout makes each frag a
// single dwordx4 per lane; a wave's load = 16 rows x 64B full cache lines),
// register-double-buffered over 32 k-steps, fully unrolled. Removes the
// __syncthreads vmcnt(0) drain that capped the LDS structure at ~22% MfmaUtil.
// 128x128 block tile, 4 waves (2x2), 4x4 mfma_f32_16x16x32_bf16 per wave.
// ---------------------------------------------------------------------------
__global__ __launch_bounds__(256) void gemm_kernel(
    const unsigned short* __restrict__ Xb,   // [8][4096][1024] bf16
    const unsigned short* __restrict__ Wt,   // [8][1024(l)][1024(d1)] bf16
    const float* __restrict__ bias,          // [8][1024]
    float* __restrict__ out) {               // [4096][8][1024]
  const int t = threadIdx.x;
  const int wv = t >> 6;
  const int ln = t & 63;
  const int wm = wv >> 1, wn = wv & 1;
  const int lm = ln & 15;                    // m (or n) row within 16
  const int cq = ln >> 4;                    // k-chunk quad 0..3
  const int n = blockIdx.z;
  const int bm0 = blockIdx.x * 128;
  const int bn0 = blockIdx.y * 128;

  // A frag i: rows bm0+wm*64+i*16+lm, k = kk*32 + cq*8 .. +8  (16B contiguous)
  const unsigned short* A0 =
      Xb + ((size_t)n << 22) + (size_t)(bm0 + wm * 64 + lm) * 1024 + cq * 8;
  const unsigned short* B0 =
      Wt + ((size_t)n << 20) + (size_t)(bn0 + wn * 64 + lm) * 1024 + cq * 8;

  f32x4 acc[4][4];
#pragma unroll
  for (int i = 0; i < 4; i++)
#pragma unroll
    for (int j = 0; j < 4; j++) acc[i][j] = (f32x4){0.f, 0.f, 0.f, 0.f};

  short8 a[4], b[4], an[4], bn2[4];
#pragma unroll
  for (int i = 0; i < 4; i++) a[i] = *(const short8*)(A0 + (size_t)i * 16384);
#pragma unroll
  for (int j = 0; j < 4; j++) b[j] = *(const short8*)(B0 + (size_t)j * 16384);

#pragma unroll
  for (int kk = 0; kk < 31; kk++) {
    const int ko = (kk + 1) * 32;            // elements; *2B = imm offset <= 1984
#pragma unroll
    for (int i = 0; i < 4; i++)
      an[i] = *(const short8*)(A0 + (size_t)i * 16384 + ko);
#pragma unroll
    for (int j = 0; j < 4; j++)
      bn2[j] = *(const short8*)(B0 + (size_t)j * 16384 + ko);
#pragma unroll
    for (int i = 0; i < 4; i++)
#pragma unroll
      for (int j = 0; j < 4; j++)
        acc[i][j] =
            __builtin_amdgcn_mfma_f32_16x16x32_bf16(a[i], b[j], acc[i][j], 0, 0, 0);
#pragma unroll
    for (int i = 0; i < 4; i++) { a[i] = an[i]; b[i] = bn2[i]; }
  }
#pragma unroll
  for (int i = 0; i < 4; i++)
#pragma unroll
    for (int j = 0; j < 4; j++)
      acc[i][j] =
          __builtin_amdgcn_mfma_f32_16x16x32_bf16(a[i], b[j], acc[i][j], 0, 0, 0);

  // Epilogue: C/D layout col=lane&15, row=(lane>>4)*4+reg  [m89/m91]
  const int q = cq;
  const int row0 = bm0 + wm * 64 + q * 4;
  const int col0 = bn0 + wn * 64 + lm;
  float bv[4];
#pragma unroll
  for (int j = 0; j < 4; j++) bv[j] = bias[n * 1024 + col0 + j * 16];
#pragma unroll
  for (int i = 0; i < 4; i++) {
#pragma unroll
    for (int r = 0; r < 4; r++) {
      const int row = row0 + i * 16 + r;
      float* op = out + ((size_t)row * 8 + (size_t)n) * 1024;
#pragma unroll
      for (int j = 0; j < 4; j++) op[col0 + j * 16] = acc[i][j][r] + bv[j];
    }
  }
}

// ---------------------------------------------------------------------------
extern "C" void kernel_launch(void* const* d_in, const int* in_sizes, int n_in,
                              void* d_out, int out_size, void* d_ws, size_t ws_size,
                              hipStream_t stream) {
  const float* x     = (const float*)d_in[0];
  const float* U     = (const float*)d_in[1];
  const float* V     = (const float*)d_in[2];
  const float* scale = (const float*)d_in[3];
  const float* biasq = (const float*)d_in[4];
  const float* bias  = (const float*)d_in[5];
  float* out = (float*)d_out;

  // workspace: Xb bf16 [8][4096][1024] = 64 MiB, Wt bf16 [8][1024][1024] = 16 MiB
  unsigned short* Xb = (unsigned short*)d_ws;
  unsigned short* Wt = (unsigned short*)((char*)d_ws + (size_t)67108864);

  xcast_kernel<<<32768, 256, 0, stream>>>((const float4*)x, (ushort4v*)Xb);
  wgen_kernel<<<dim3(32, 32), 256, 0, stream>>>((const float4*)U, (const float4*)V,
                                                scale, biasq, Wt);
  gemm_kernel<<<dim3(32, 8, 8), 256, 0, stream>>>(Xb, Wt, bias, out);
}

// Round 5
// 453.377 us; speedup vs baseline: 1.3545x; 1.3545x over previous
//
#include <hip/hip_runtime.h>
#include <hip/hip_bf16.h>

// Problem constants
// x:(4096,8,1024) f32, U:(8,1048576,4) f32, V:(4,1048576,4) f32,
// scale:(8,1), biasq:(8,1), bias:(8,1024)  -> out:(4096,8,1024) f32
// D = 1024*1024 = 2^20, B=4096, N=8, K=4, BW=4, T=1.0

typedef __attribute__((ext_vector_type(8))) short short8;
typedef __attribute__((ext_vector_type(4))) float f32x4;
typedef __attribute__((ext_vector_type(4))) unsigned short ushort4v;
typedef __attribute__((ext_vector_type(2))) unsigned int uint2v;

__device__ __forceinline__ unsigned short f2bf(float f) {
  union { float f; unsigned u; } a; a.f = f;
  unsigned u = a.u;
  u += 0x7fffu + ((u >> 16) & 1u);   // RNE; inputs are finite
  return (unsigned short)(u >> 16);
}

__device__ __forceinline__ unsigned pk2(float a, float b) {
  __hip_bfloat162 h = __float22bfloat162_rn(make_float2(a, b));
  union { __hip_bfloat162 h; unsigned u; } c; c.h = h;
  return c.u;
}

// ---------------------------------------------------------------------------
// Kernel 1: weight synthesis -> W^T bf16: Wt[n][l=d2][d1]
// Phase 2 vectorized: ushort4 (8B) stores, 8/thread (was 32 scalar 2B).
// ---------------------------------------------------------------------------
__global__ __launch_bounds__(256) void wgen_kernel(
    const float4* __restrict__ U4, const float4* __restrict__ V4,
    const float* __restrict__ scale, const float* __restrict__ biasq,
    unsigned short* __restrict__ Wt) {
  __shared__ float tiles[8][32][33];
  const int t = threadIdx.x;
  const int d1_0 = blockIdx.x * 32;
  const int d2_0 = blockIdx.y * 32;
#pragma unroll
  for (int i = 0; i < 4; i++) {
    const int e = t + 256 * i;
    const int r = e >> 5, c = e & 31;          // r: d1 offset, c: d2 offset
    const size_t d = (size_t)(d1_0 + r) * 1024 + (size_t)(d2_0 + c);
    float4 u[8];
#pragma unroll
    for (int nn = 0; nn < 8; nn++) u[nn] = U4[((size_t)nn << 20) + d];
    float integ[8];
#pragma unroll
    for (int nn = 0; nn < 8; nn++) integ[nn] = 0.f;
#pragma unroll
    for (int b = 0; b < 4; b++) {
      const float4 v = V4[((size_t)b << 20) + d];
      const float pw = (float)(1 << b);
#pragma unroll
      for (int nn = 0; nn < 8; nn++) {
        float th = u[nn].x * v.x + u[nn].y * v.y + u[nn].z * v.z + u[nn].w * v.w;
        th = fminf(10.f, fmaxf(-10.f, th));
        integ[nn] += pw / (1.f + __expf(-th));
      }
    }
#pragma unroll
    for (int nn = 0; nn < 8; nn++) tiles[nn][r][c] = integ[nn];
  }
  __syncthreads();
  const int orow = t >> 3;                     // d2 offset 0..31
  const int oc0 = (t & 7) * 4;                 // d1 offset (x4)
#pragma unroll
  for (int nn = 0; nn < 8; nn++) {
    const float sc = scale[nn], bq = biasq[nn];
    ushort4v o;
    o.x = f2bf(sc * (tiles[nn][oc0 + 0][orow] - bq - 16.f));
    o.y = f2bf(sc * (tiles[nn][oc0 + 1][orow] - bq - 16.f));
    o.z = f2bf(sc * (tiles[nn][oc0 + 2][orow] - bq - 16.f));
    o.w = f2bf(sc * (tiles[nn][oc0 + 3][orow] - bq - 16.f));
    *(ushort4v*)(Wt + ((size_t)nn << 20) + (size_t)(d2_0 + orow) * 1024 +
                 (size_t)(d1_0 + oc0)) = o;
  }
}

// ---------------------------------------------------------------------------
// Kernel 2: batched bf16 GEMM, R2 structure (BK=64, XOR chunk swizzle,
// 128x128 tile, 4 waves 2x2, 4x4 mfma_f32_16x16x32_bf16; 130 us verified)
// with A staged DIRECTLY from x fp32: coalesced dwordx4 loads (16 lanes =
// one row's 256B), v_cvt_pk_bf16_f32 pack, ds_write_b64 into the identical
// swizzled layout. B staged via global_load_lds from Wt as before.
// Eliminates the separate xcast kernel + 64 MB of workspace traffic.
// ---------------------------------------------------------------------------
#define AS1(p) ((const __attribute__((address_space(1))) void*)(p))
#define AS3(p) ((__attribute__((address_space(3))) void*)(p))

__global__ __launch_bounds__(256) void gemm_kernel(
    const float* __restrict__ X,             // [4096][8][1024] fp32
    const unsigned short* __restrict__ Wt,   // [8][1024(l)][1024(d1)] bf16
    const float* __restrict__ bias,          // [8][1024]
    float* __restrict__ out) {               // [4096][8][1024]
  __shared__ unsigned short As[128 * 64];    // 16 KiB
  __shared__ unsigned short Bs[128 * 64];    // 16 KiB
  const int t = threadIdx.x;
  const int wv = t >> 6;
  const int ln = t & 63;
  const int n = blockIdx.z;
  const int bm0 = blockIdx.x * 128;
  const int bn0 = blockIdx.y * 128;

  // ---- A staging geometry: round r_i covers rows ar+16*r_i; 16 lanes/row.
  const int ar = t >> 4;                     // row 0..15 (+16*r_i)
  const int f = t & 15;                      // float4 index within 64-float span
  const int a_cg = f >> 1;                   // bf16 chunk 0..7
  const int a_half = f & 1;                  // low/high half of chunk
  // x[b][n][k]: row b = bm0 + ar + 16*r_i
  const float* Ax = X + ((size_t)(bm0 + ar) * 8 + (size_t)n) * 1024 + f * 4;
  // LDS slot = chunk ^ (row&7); row&7 == ar&7 (16*r_i is 0 mod 8)
  unsigned short* wA = As + ar * 64 + ((a_cg ^ (ar & 7)) * 8) + a_half * 4;

  // ---- B staging geometry (global_load_lds, unchanged from R2)
  const int sr = wv * 8 + (ln >> 3);                 // 0..31
  const int sk = (((ln & 7) ^ (sr & 7)) * 8);        // swizzled global chunk
  const unsigned short* bg =
      Wt + ((size_t)n << 20) + (size_t)(bn0 + sr) * 1024 + sk;
  unsigned short* lB = Bs + wv * 512;                // wave-uniform LDS base

  // ---- fragment-read geometry (unchanged from R2)
  const int wm = wv >> 1, wn = wv & 1;
  const int lm = ln & 15;
  const int cq = ln >> 4;                            // k-quarter 0..3
  const int sw = lm & 7;                             // row swizzle key
  const unsigned short* a_rd = As + (wm * 64 + lm) * 64;
  const unsigned short* b_rd = Bs + (wn * 64 + lm) * 64;

  f32x4 acc[4][4];
#pragma unroll
  for (int i = 0; i < 4; i++)
#pragma unroll
    for (int j = 0; j < 4; j++) acc[i][j] = (f32x4){0.f, 0.f, 0.f, 0.f};

  for (int k0 = 0; k0 < 1024; k0 += 64) {
    // B: async global->LDS (in flight during A cvt)
#pragma unroll
    for (int r = 0; r < 4; r++)
      __builtin_amdgcn_global_load_lds(AS1(bg + (size_t)(32 * r) * 1024 + k0),
                                       AS3(lB + r * 2048), 16, 0, 0);
    // A: fp32 load -> bf16 pack -> LDS (two batches of 4 rounds, caps VGPRs)
#pragma unroll
    for (int h2 = 0; h2 < 2; h2++) {
      float4 av[4];
#pragma unroll
      for (int i = 0; i < 4; i++)
        av[i] = *(const float4*)(Ax + k0 + (size_t)(h2 * 4 + i) * 131072);
#pragma unroll
      for (int i = 0; i < 4; i++) {
        uint2v p;
        p.x = pk2(av[i].x, av[i].y);
        p.y = pk2(av[i].z, av[i].w);
        *(uint2v*)(wA + (h2 * 4 + i) * 1024) = p;
      }
    }
    __syncthreads();
#pragma unroll
    for (int half = 0; half < 2; half++) {
      const int off = ((half * 4 + cq) ^ sw) * 8;    // swizzled 16B chunk
      short8 af[4], bfr[4];
#pragma unroll
      for (int i = 0; i < 4; i++) af[i] = *(const short8*)(a_rd + i * 1024 + off);
#pragma unroll
      for (int j = 0; j < 4; j++) bfr[j] = *(const short8*)(b_rd + j * 1024 + off);
#pragma unroll
      for (int i = 0; i < 4; i++)
#pragma unroll
        for (int j = 0; j < 4; j++)
          acc[i][j] = __builtin_amdgcn_mfma_f32_16x16x32_bf16(af[i], bfr[j],
                                                              acc[i][j], 0, 0, 0);
    }
    __syncthreads();
  }

  // Epilogue: C/D layout col=lane&15, row=(lane>>4)*4+reg  [m89/m91]
  const int q = ln >> 4;
  const int row0 = bm0 + wm * 64 + q * 4;
  const int col0 = bn0 + wn * 64 + lm;
  float bv[4];
#pragma unroll
  for (int j = 0; j < 4; j++) bv[j] = bias[n * 1024 + col0 + j * 16];
#pragma unroll
  for (int i = 0; i < 4; i++) {
#pragma unroll
    for (int r = 0; r < 4; r++) {
      const int row = row0 + i * 16 + r;
      float* op = out + ((size_t)row * 8 + (size_t)n) * 1024;
#pragma unroll
      for (int j = 0; j < 4; j++) op[col0 + j * 16] = acc[i][j][r] + bv[j];
    }
  }
}

// ---------------------------------------------------------------------------
extern "C" void kernel_launch(void* const* d_in, const int* in_sizes, int n_in,
                              void* d_out, int out_size, void* d_ws, size_t ws_size,
                              hipStream_t stream) {
  const float* x     = (const float*)d_in[0];
  const float* U     = (const float*)d_in[1];
  const float* V     = (const float*)d_in[2];
  const float* scale = (const float*)d_in[3];
  const float* biasq = (const float*)d_in[4];
  const float* bias  = (const float*)d_in[5];
  float* out = (float*)d_out;

  // workspace: Wt bf16 [8][1024][1024] = 16 MiB
  unsigned short* Wt = (unsigned short*)d_ws;

  wgen_kernel<<<dim3(32, 32), 256, 0, stream>>>((const float4*)U, (const float4*)V,
                                                scale, biasq, Wt);
  gemm_kernel<<<dim3(32, 8, 8), 256, 0, stream>>>(x, Wt, bias, out);
}